// Round 29
// baseline (616.993 us; speedup 1.0000x reference)
//
#include <hip/hip_runtime.h>
#include <math.h>

#define TWO_PI 6.283185307179586f

// HARNESS MODEL (verified R8-R28): d_out = 33,362,176 f32 = Re(out), [bc][l][m].
// Math: xr[c][k][m] = (2pi/720) * sum_n x[c][k][n] * cos(2pi n m/720)
//       out[c][l][m] = sum_k xr[c][k][m] * W[m][l][k]
// R29: s1 rebuilt BARRIER-FREE: full-K B (64 m-rows x 192 k, padded rows)
// preloaded ONCE into 50 KB LDS; k-loop = per-lane A loads + in-register
// double-fold/split (R26/R28-proven algebra) + bank-balanced B reads + MFMA,
// zero barriers, fully unrolled. Fixes R22's failure (12x A redundancy at
// m-tile 32); here m-tile 64 -> 6x redundancy on half the K. R19's failure
// (20 loads/iter unpipelined at 44 VGPR) avoided: only 8 loads/iter,
// launch_bounds(256,3). fold_uv/s2/transpose = R28 verbatim.

typedef __attribute__((ext_vector_type(8))) short bf16x8;
typedef __attribute__((ext_vector_type(4))) float f32x4;

union BFU { uint4 u; bf16x8 v; };

__device__ inline unsigned short f2bf(float f) {
    union { float f; unsigned int u; } v; v.f = f;
    unsigned int u = v.u;
    return (unsigned short)((u + 0x7fffu + ((u >> 16) & 1u)) >> 16);  // RNE
}
__device__ inline float bf2f(unsigned short h) {
    union { unsigned int u; float f; } v; v.u = ((unsigned int)h) << 16;
    return v.f;
}
__device__ inline unsigned int packhl(float v) {
    unsigned short h = f2bf(v);
    unsigned short l = f2bf(v - bf2f(h));
    return (unsigned int)h | ((unsigned int)l << 16);
}
__device__ inline float unpackhl(unsigned int p) {
    return bf2f((unsigned short)(p & 0xffffu)) + bf2f((unsigned short)(p >> 16));
}
__device__ inline void split2(float a, float b, unsigned int& hh, unsigned int& ll) {
    unsigned short ha = f2bf(a), hb = f2bf(b);
    unsigned short la = f2bf(a - bf2f(ha)), lb = f2bf(b - bf2f(hb));
    hh = (unsigned int)ha | ((unsigned int)hb << 16);
    ll = (unsigned int)la | ((unsigned int)lb << 16);
}
// truncation split (R17/R20-proven for s1 A-path)
__device__ inline void split2t(float a, float b, unsigned int& hh, unsigned int& ll) {
    union { float f; unsigned int u; } ua, ub, fa, fb, la, lb;
    ua.f = a; ub.f = b;
    hh = (ua.u >> 16) | (ub.u & 0xffff0000u);
    fa.u = ua.u & 0xffff0000u;
    fb.u = ub.u & 0xffff0000u;
    la.f = a - fa.f;
    lb.f = b - fb.f;
    ll = (la.u >> 16) | (lb.u & 0xffff0000u);
}
// async global->LDS, 16B per lane; dest = wave-uniform base + lane*16
__device__ inline void gload_lds16(const void* g, void* l) {
    __builtin_amdgcn_global_load_lds(
        (const __attribute__((address_space(1))) unsigned int*)g,
        (__attribute__((address_space(3))) unsigned int*)l, 16, 0, 0);
}
// bijective chunked XCD swizzle (m204)
__device__ inline int xcd_work(int bid, int nwg) {
    int q = nwg >> 3, r = nwg & 7;
    int xcd = bid & 7, ord = bid >> 3;
    return (xcd < r ? xcd * (q + 1) : r * (q + 1) + (xcd - r) * q) + ord;
}

// ---- tables: Eh/El[row=g*192+mg][n<192] bf16, m=2*mg+g, val=sigma*c(n,m),
//      n==180 halved (self-pair), zero for n>180 or m>360 ----
__global__ void build_ect(unsigned short* __restrict__ Eh,
                          unsigned short* __restrict__ El) {
    const float sigma = TWO_PI / 720.0f;
    const int total = 384 * 192;
    for (int i = blockIdx.x * blockDim.x + threadIdx.x; i < total;
         i += gridDim.x * blockDim.x) {
        int row = i / 192, n = i % 192;
        int g = row / 192 ? 1 : 0;
        int mg = row - g * 192;
        int m = 2 * mg + g;
        float v = 0.f;
        if (m <= 360 && n <= 180) {
            int r = (n * m) % 720;  // exact phase reduction
            v = sigma * cosf((float)r * (TWO_PI / 720.0f));
            if (n == 180) v *= 0.5f;
        }
        unsigned short h = f2bf(v);
        Eh[i] = h;
        El[i] = f2bf(v - bf2f(h));
    }
}

// ---------------- stage 1: double-folded DFT, barrier-free, K=192 ----------------
// grid = qt*6 (swizzled): q0=(work/6)*64, tile=work%6 -> grp=tile/3, m0t=(tile%3)*64.
// Block: 4 waves x 16 q-rows; per wave 64 m-rows (4 x 16x16 frags).
__global__ __launch_bounds__(256, 3) void s1_mfma(
    const float* __restrict__ x, const unsigned short* __restrict__ Eh,
    const unsigned short* __restrict__ El, unsigned int* __restrict__ xrp,
    const int Q) {
    __shared__ short Bt[2][64][200];   // 51,200 B; rows padded 192->200 shorts

    const int work = xcd_work(blockIdx.x, gridDim.x);
    const int q0 = (work / 6) * 64;
    const int tile = work % 6;
    const int grp = tile / 3;          // 0 = even m, 1 = odd m
    const int m0t = (tile % 3) * 64;   // mg tile base
    const int t = threadIdx.x;
    const int lane = t & 63, wv = t >> 6;
    const int lr = lane & 15, lk = lane >> 4;

    // ---- B preload once: 3200 16B chunks (25 per padded row, 24 carry data) ----
#pragma unroll
    for (int i = 0; i < 13; ++i) {
        int id = t + i * 256;
        if (id < 3200) {
            int tab = id / 1600, rem = id % 1600;
            int row = rem / 25, c = rem % 25;
            int cs = (c < 24) ? c : 23;   // pad chunk: duplicate source, never read
            const unsigned short* src =
                (tab ? El : Eh) + (size_t)(grp * 192 + m0t + row) * 192 + cs * 8;
            gload_lds16(src, (char*)&Bt[0][0][0] + id * 16);
        }
    }
    __syncthreads();   // B resident for whole kernel; only barrier

    const int aq = q0 + wv * 16 + lr;
    const bool qv = (aq < Q);
    const float* arow = x + (size_t)(qv ? aq : 0) * 720;
    const float sgn = grp ? -1.f : 1.f;

    f32x4 acc[4];
#pragma unroll
    for (int nj = 0; nj < 4; ++nj)
#pragma unroll
        for (int r = 0; r < 4; ++r) acc[nj][r] = 0.f;

    // ---- main loop: 6 iterations, no barriers, no LDS writes ----
#pragma unroll
    for (int it = 0; it < 6; ++it) {
        const int n0 = it * 32 + lk * 8;   // 0..184
        // raw loads (8 float4 per lane)
        float4 fa = *(const float4*)(arow + n0);          // x[n..]
        float4 fb = *(const float4*)(arow + n0 + 4);
        float4 ga = *(const float4*)(arow + 360 + n0);    // x[360+n..]
        float4 gb = *(const float4*)(arow + 364 + n0);
        float4 sa = *(const float4*)(arow + 353 - n0);    // x[360-n] reversed
        float4 sb = *(const float4*)(arow + 357 - n0);
        float4 ra, rb;                                    // x[720-n] reversed
        if (n0 >= 8) {
            ra = *(const float4*)(arow + 713 - n0);
            rb = *(const float4*)(arow + 717 - n0);
        } else {
            float tm[8];
#pragma unroll
            for (int i = 0; i < 8; ++i)
                tm[i] = (7 - i >= 1) ? arow[713 + i] : 0.f;   // x[720-j]=0 at j=0
            ra = make_float4(tm[0], tm[1], tm[2], tm[3]);
            rb = make_float4(tm[4], tm[5], tm[6], tm[7]);
        }
        float f[8] = {fa.x, fa.y, fa.z, fa.w, fb.x, fb.y, fb.z, fb.w};
        float g[8] = {ga.x, ga.y, ga.z, ga.w, gb.x, gb.y, gb.z, gb.w};
        float rv[8] = {rb.w, rb.z, rb.y, rb.x, ra.w, ra.z, ra.y, ra.x};
        float sv[8] = {sb.w, sb.z, sb.y, sb.x, sa.w, sa.z, sa.y, sa.x};
        float y[8];
#pragma unroll
        for (int j = 0; j < 8; ++j) {
            int n = n0 + j;
            float base = f[j] + rv[j];                     // y1[n]
            float pair = sv[j] + ((n == 0) ? 0.f : g[j]);  // y1[360-n]
            float val = base + sgn * pair;
            y[j] = (qv && n <= 180) ? val : 0.f;
        }
        BFU hu, lu;
        split2t(y[0], y[1], hu.u.x, lu.u.x);
        split2t(y[2], y[3], hu.u.y, lu.u.y);
        split2t(y[4], y[5], hu.u.z, lu.u.z);
        split2t(y[6], y[7], hu.u.w, lu.u.w);
        const bf16x8 ah = hu.v, al = lu.v;

#pragma unroll
        for (int nj = 0; nj < 4; ++nj) {
            const int brow = nj * 16 + lr;
            bf16x8 bh = *(const bf16x8*)&Bt[0][brow][it * 32 + lk * 8];
            bf16x8 bl = *(const bf16x8*)&Bt[1][brow][it * 32 + lk * 8];
            acc[nj] = __builtin_amdgcn_mfma_f32_16x16x32_bf16(ah, bh, acc[nj], 0, 0, 0);
            acc[nj] = __builtin_amdgcn_mfma_f32_16x16x32_bf16(ah, bl, acc[nj], 0, 0, 0);
            acc[nj] = __builtin_amdgcn_mfma_f32_16x16x32_bf16(al, bh, acc[nj], 0, 0, 0);
        }
    }

    // epilogue: D col = mg (m = 2*mg + grp), row = q  (verified mapping)
#pragma unroll
    for (int nj = 0; nj < 4; ++nj) {
        int mg = m0t + nj * 16 + lr;
        int m = 2 * mg + grp;
        if (m >= 361) continue;
        size_t base = (size_t)m * Q;
#pragma unroll
        for (int reg = 0; reg < 4; ++reg) {
            int q = q0 + wv * 16 + lk * 4 + reg;
            if (q < Q) xrp[base + q] = packhl(acc[nj][reg]);
        }
    }
}

// ---------------- fold_uv: u/v packed planes [m][bc][192] from xrp ----------------
__global__ __launch_bounds__(256) void fold_uv(const unsigned int* __restrict__ xrp,
                                               unsigned int* __restrict__ up,
                                               unsigned int* __restrict__ vp,
                                               const int CH) {
    const int total = 361 * CH * 192;
    const int Q = CH * 361;
    for (int i = blockIdx.x * blockDim.x + threadIdx.x; i < total;
         i += gridDim.x * blockDim.x) {
        int m = i / (CH * 192);
        int rem = i - m * (CH * 192);
        int bc = rem / 192;
        int k = rem - bc * 192;
        float u = 0.f, v = 0.f;
        if (k <= 180) {
            size_t base = (size_t)m * Q + (size_t)bc * 361;
            float x1 = unpackhl(xrp[base + k]);
            if (k < 180) {
                float x2 = unpackhl(xrp[base + 360 - k]);
                u = x1 + x2;
                v = x1 - x2;
            } else {
                u = x1;
                v = x1;
            }
        }
        up[i] = packhl(u);
        vp[i] = packhl(v);
    }
}

// ---------------- stage 2: parity-folded per-m GEMM, K=192 (6 iters) ----------------
// 12 blocks/m: 2 bc-halves x 2 parity groups x 3 lg-tiles; l = 2*lg + par.
__global__ __launch_bounds__(256, 4) void s2_mfma(
    const unsigned int* __restrict__ up, const unsigned int* __restrict__ vp,
    const float* __restrict__ W, float* __restrict__ stg, const int CH) {
    __shared__ short Ah[128][40], Al[128][40];   // 10 KB each
    __shared__ short Bh[64][40], Bl[64][40];     // 5 KB each -> 30 KB

    const int work = xcd_work(blockIdx.x, gridDim.x);
    const int m = work / 12;
    const int rem = work % 12;
    const int half = rem / 6;
    const int r2 = rem % 6;
    const int g = r2 / 3, lgt = r2 % 3;
    const int lg0 = lgt * 64;
    const int par = (g + m) & 1;
    if (2 * (lg0 + 63) + par < m) return;   // dead tile: transpose zero-fills
    const int bcbase = half * 128;
    if (bcbase >= CH) return;
    const int t = threadIdx.x;
    const int lane = t & 63, wv = t >> 6;
    const int lr = lane & 15, lk = lane >> 4;
    const int wbc = wv >> 1, wl = wv & 1;

    const unsigned int* Am = (g ? vp : up) + (size_t)m * CH * 192;
    const float* Wm = W + (size_t)m * 130321;

    f32x4 acc[4][2];
#pragma unroll
    for (int fi = 0; fi < 4; ++fi)
#pragma unroll
        for (int ni = 0; ni < 2; ++ni)
#pragma unroll
            for (int r = 0; r < 4; ++r) acc[fi][ni][r] = 0.f;

    unsigned int pa0[8], pa1[8];
    float wva[4], wvb[4];

#define S2_LOADR(K0)                                                          \
    {                                                                         \
        _Pragma("unroll") for (int i = 0; i < 8; ++i) {                       \
            int id = t + i * 256;                                             \
            int r = id >> 4, kp = id & 15;                                    \
            int bc = bcbase + r, kg = (K0) + kp * 2;                          \
            unsigned int p0 = 0, p1 = 0;                                      \
            if (bc < CH) {                                                    \
                size_t base = (size_t)bc * 192;                               \
                p0 = Am[base + kg];                                           \
                p1 = Am[base + kg + 1];                                       \
            }                                                                 \
            pa0[i] = p0; pa1[i] = p1;                                         \
        }                                                                     \
        _Pragma("unroll") for (int i = 0; i < 4; ++i) {                       \
            int id = t + i * 256;                                             \
            int r = id >> 4, kp = id & 15;                                    \
            int l = 2 * (lg0 + r) + par, kg = (K0) + kp * 2;                  \
            float va = 0.f, vb = 0.f;                                         \
            if (l < 361) {                                                    \
                size_t base = (size_t)l * 361;                                \
                if (kg <= 180) va = Wm[base + kg];                            \
                if (kg + 1 <= 180) vb = Wm[base + kg + 1];                    \
            }                                                                 \
            wva[i] = va; wvb[i] = vb;                                         \
        }                                                                     \
    }
#define S2_WRITES()                                                           \
    {                                                                         \
        _Pragma("unroll") for (int i = 0; i < 8; ++i) {                       \
            int id = t + i * 256;                                             \
            int r = id >> 4, kp = id & 15;                                    \
            *(unsigned int*)&Ah[r][kp * 2] =                                  \
                (pa0[i] & 0xffffu) | (pa1[i] << 16);                          \
            *(unsigned int*)&Al[r][kp * 2] =                                  \
                (pa0[i] >> 16) | (pa1[i] & 0xffff0000u);                      \
        }                                                                     \
        _Pragma("unroll") for (int i = 0; i < 4; ++i) {                       \
            int id = t + i * 256;                                             \
            int r = id >> 4, kp = id & 15;                                    \
            unsigned int hh, ll;                                              \
            split2(wva[i], wvb[i], hh, ll);                                   \
            *(unsigned int*)&Bh[r][kp * 2] = hh;                              \
            *(unsigned int*)&Bl[r][kp * 2] = ll;                              \
        }                                                                     \
    }

    S2_LOADR(0);
    S2_WRITES();
    __syncthreads();
    for (int it = 0; it < 6; ++it) {
        if (it + 1 < 6) S2_LOADR((it + 1) * 32);
#pragma unroll
        for (int fi = 0; fi < 4; ++fi) {
            bf16x8 ah = *(const bf16x8*)&Ah[wbc * 64 + fi * 16 + lr][lk * 8];
            bf16x8 al = *(const bf16x8*)&Al[wbc * 64 + fi * 16 + lr][lk * 8];
#pragma unroll
            for (int ni = 0; ni < 2; ++ni) {
                bf16x8 bh = *(const bf16x8*)&Bh[wl * 32 + ni * 16 + lr][lk * 8];
                bf16x8 bl = *(const bf16x8*)&Bl[wl * 32 + ni * 16 + lr][lk * 8];
                acc[fi][ni] = __builtin_amdgcn_mfma_f32_16x16x32_bf16(ah, bh, acc[fi][ni], 0, 0, 0);
                acc[fi][ni] = __builtin_amdgcn_mfma_f32_16x16x32_bf16(ah, bl, acc[fi][ni], 0, 0, 0);
                acc[fi][ni] = __builtin_amdgcn_mfma_f32_16x16x32_bf16(al, bh, acc[fi][ni], 0, 0, 0);
            }
        }
        __syncthreads();
        if (it + 1 < 6) {
            S2_WRITES();
            __syncthreads();
        }
    }

    // epilogue: stg[(m*CH+bc)*361 + l],  l = 2*(lg0+row)+par
#pragma unroll
    for (int fi = 0; fi < 4; ++fi) {
#pragma unroll
        for (int ni = 0; ni < 2; ++ni) {
            int l = 2 * (lg0 + wl * 32 + ni * 16 + lr) + par;
#pragma unroll
            for (int reg = 0; reg < 4; ++reg) {
                int bc = bcbase + wbc * 64 + fi * 16 + lk * 4 + reg;
                if (bc < CH && l < 361)
                    stg[((size_t)m * CH + bc) * 361 + l] = acc[fi][ni][reg];
            }
        }
    }
}

// ---------------- transpose stg [m][q'] -> out, zero-filling dead parity-tiles ----------------
__global__ __launch_bounds__(256) void transpose_out(const float* __restrict__ stg,
                                                     float* __restrict__ out,
                                                     const int c0, const int CH) {
    __shared__ float tile[32][33];
    const int Q = CH * 361;
    const int m0 = blockIdx.y * 32, q0 = blockIdx.x * 32;
    const int tx = threadIdx.x & 31, ty = threadIdx.x >> 5;
    for (int i = ty; i < 32; i += 8) {
        int mm = m0 + i, q = q0 + tx;
        float v = 0.f;
        if (mm < 361 && q < Q) {
            int l = q % 361;
            int par = l & 1;          // parity of l indexes the s2 tile (R28 fix)
            int lg = l >> 1;
            if (2 * (lg | 63) + par >= mm) v = stg[(size_t)mm * Q + q];
        }
        tile[i][tx] = v;
    }
    __syncthreads();
    for (int i = ty; i < 32; i += 8) {
        int q = q0 + i, mm = m0 + tx;
        if (mm < 361 && q < Q)
            out[((size_t)c0 * 361 + q) * 361 + mm] = tile[tx][i];
    }
}

extern "C" void kernel_launch(void* const* d_in, const int* in_sizes, int n_in,
                              void* d_out, int out_size, void* d_ws, size_t ws_size,
                              hipStream_t stream) {
    (void)out_size;
    // select inputs by element count: x = 66,539,520; W = 47,045,881
    const float* x = (const float*)d_in[0];
    const float* W = (const float*)d_in[1];
    if (n_in >= 2 && (in_sizes[0] == 47045881 || in_sizes[1] == 66539520)) {
        x = (const float*)d_in[1];
        W = (const float*)d_in[0];
    }
    float* out = (float*)d_out;

    // ws layout (bytes): Eh [384][192] | El | xrp | up | vp | stg
    const size_t offEh = 0;
    const size_t offEl = 147456;                 // 384*192*2
    const size_t offData = 294912;

    // per-CH elements: xrp CH*130321 u32; up/vp CH*69312 u32 each; stg CH*130321 f32
    const int cands[6] = {256, 128, 64, 32, 16, 8};
    int CH = 0;
    for (int i = 0; i < 6; ++i) {
        size_t need = offData + (size_t)cands[i] * (130321ull * 2 + 69312ull * 2) * 4;
        if (need <= ws_size) { CH = cands[i]; break; }
    }
    if (!CH) return;  // workspace too small: fail visibly, don't fault

    unsigned short* Eh = (unsigned short*)((char*)d_ws + offEh);
    unsigned short* El = (unsigned short*)((char*)d_ws + offEl);
    unsigned int* xrp = (unsigned int*)((char*)d_ws + offData);
    unsigned int* up = xrp + (size_t)CH * 130321;
    unsigned int* vp = up + (size_t)CH * 69312;
    float* stg = (float*)(vp + (size_t)CH * 69312);

    build_ect<<<256, 256, 0, stream>>>(Eh, El);

    const int Q = CH * 361;
    const int qt = (Q + 63) / 64;
    for (int c0 = 0; c0 < 256; c0 += CH) {
        s1_mfma<<<qt * 6, 256, 0, stream>>>(
            x + (size_t)c0 * 361 * 720, Eh, El, xrp, Q);
        fold_uv<<<8192, 256, 0, stream>>>(xrp, up, vp, CH);
        s2_mfma<<<361 * 12, 256, 0, stream>>>(up, vp, W, stg, CH);
        transpose_out<<<dim3((Q + 31) / 32, 12), 256, 0, stream>>>(stg, out, c0, CH);
    }
}